// Round 12
// baseline (346.947 us; speedup 1.0000x reference)
//
#include <hip/hip_runtime.h>

// ---------------------------------------------------------------------------
// CrossAttentionMM on MI355X (gfx950), bf16 MFMA pipeline.
// B=4, SQ=4096, SKV=1024, QDIM=1024, CDIM=768, H=16, D=64, INNER=1024.
// R17: GEMMs ported to the m97/m103 128^2 structure (912 TF ref'd): 256 thr
// (2x2 waves, 64x64/wave), BK=32, triple-buffered 48KB LDS -> 3 blocks/CU
// (6 waves/SIMD: cross-block TLP hides barrier drains, m114), prefetch
// distance 2 + vmcnt(4) (R6 skeleton), COALESCED staging (R15 lesson:
// thread t -> row t>>2, chunk t&3; 16x64B txns/load; LDS dest linear).
// Linear row-major [128][32] LDS, no swizzle: 64B row stride gives even
// bank distribution on frag reads by construction.
// Previous 256^2 8-phase core ran 1 block/CU, ~420 TF combined (~200us).
// attn v9 (115.5us stable) / cvt / twt / XCD swizzle unchanged.
// ---------------------------------------------------------------------------

typedef unsigned short u16;
typedef unsigned int u32;
typedef __bf16 bf16x8 __attribute__((ext_vector_type(8)));
typedef float float4v __attribute__((ext_vector_type(4)));
typedef _Float16 half4 __attribute__((ext_vector_type(4)));
typedef _Float16 half2v __attribute__((ext_vector_type(2)));
typedef __attribute__((address_space(1))) void as1_void;
typedef __attribute__((address_space(3))) void as3_void;

__device__ __forceinline__ u16 f2bf(float f) {
  unsigned u = __float_as_uint(f);
  u += 0x7FFF + ((u >> 16) & 1);   // RTNE
  return (u16)(u >> 16);
}

// async global->LDS, 16B per lane. LDS dest = wave-uniform base + lane*16.
__device__ __forceinline__ void async16(const u16* g, u16* l) {
  __builtin_amdgcn_global_load_lds((as1_void*)(void*)g, (as3_void*)l, 16, 0, 0);
}

// gfx9 waitcnt imm: vmcnt[3:0]=imm[3:0], exp=imm[6:4], lgkm=imm[11:8], vmcnt[5:4]=imm[15:14]
#define WAITCNT_VM8 0xF78   // vmcnt(8), lgkm/exp no-wait
#define WAITCNT_VM4 0xF74   // vmcnt(4)
#define WAITCNT_VM0 0xF70   // vmcnt(0)

// ---------------- fp32 -> bf16 cast: x then ctx, one launch ----------------
__global__ void cvt_kernel(const float* __restrict__ x, u16* __restrict__ xbf,
                           const float* __restrict__ ctx, u16* __restrict__ ctxbf) {
  int i = blockIdx.x * 256 + threadIdx.x;
  const float* in; u16* out; int j;
  if (i < 4194304) { in = x; out = xbf; j = i; }
  else if (i < 4980736) { in = ctx; out = ctxbf; j = i - 4194304; }
  else return;
  float4 v = ((const float4*)in)[j];
  ushort4 o;
  o.x = f2bf(v.x); o.y = f2bf(v.y); o.z = f2bf(v.z); o.w = f2bf(v.w);
  ((ushort4*)out)[j] = o;
}

// ---------------- all 4 weights: W[K,N] fp32 -> Wt[N,K] bf16, one launch ----
__global__ void twt_kernel(const float* __restrict__ Wq, const float* __restrict__ Wk,
                           const float* __restrict__ Wv, const float* __restrict__ Wo,
                           u16* __restrict__ WqT, u16* __restrict__ WkT,
                           u16* __restrict__ WvT, u16* __restrict__ WoT) {
  __shared__ u16 t[32][33];
  int z = blockIdx.z;
  const float* W = z == 0 ? Wq : z == 1 ? Wk : z == 2 ? Wv : Wo;
  u16* Wt = z == 0 ? WqT : z == 1 ? WkT : z == 2 ? WvT : WoT;
  int Kd = (z == 1 || z == 2) ? 768 : 1024;
  int k0 = blockIdx.y * 32;
  if (k0 >= Kd) return;
  int tx = threadIdx.x, ty = threadIdx.y;
  int n0 = blockIdx.x * 32;
#pragma unroll
  for (int i = 0; i < 4; i++)
    t[ty + i * 8][tx] = f2bf(W[(size_t)(k0 + ty + i * 8) * 1024 + n0 + tx]);
  __syncthreads();
#pragma unroll
  for (int i = 0; i < 4; i++)
    Wt[(size_t)(n0 + ty + i * 8) * Kd + k0 + tx] = t[tx][ty + i * 8];
}

// ---------------------------------------------------------------------------
// 128x128 / BK=32 GEMM core (C = A * Bt^T), bf16 inputs. m97/m103 structure:
// 256 threads (2x2 waves, 64x64 out each, acc[4][4]); triple-buffered LDS
// [3][2][128][32] (48KB -> 3 blocks/CU); prefetch distance 2; vmcnt(4);
// one barrier per K-step. Staging coalesced: thread t -> row t>>2, chunk t&3
// (16 x 64B txns per wave-load); LDS dest = linear base + lane*16B.
// ---------------------------------------------------------------------------
__device__ __forceinline__ void gemm128_core(const u16* __restrict__ A,
                                             const u16* __restrict__ Bt, int K,
                                             int m0, int n0, float4v acc[4][4]) {
  __shared__ __align__(16) u16 L[3][2][128][32];   // 48 KiB
  int tid = threadIdx.x;
  int w = tid >> 6, lane = tid & 63;
  int l15 = lane & 15, quad = lane >> 4;
  int wm = (w >> 1) * 64, wn = (w & 1) * 64;

  const u16* pA = A + (size_t)(m0 + (tid >> 2)) * K + (tid & 3) * 8;
  const u16* pB = Bt + (size_t)(n0 + (tid >> 2)) * K + (tid & 3) * 8;
  size_t r64 = (size_t)64 * K;     // +64 rows (u16 elems)
  int dofs = tid * 8;              // u16 offset within [128][32] (linear fill)

#define STG(buf, t)                                                            \
  do {                                                                         \
    const u16* sa = pA + (size_t)(t) * 32;                                     \
    const u16* sb = pB + (size_t)(t) * 32;                                     \
    async16(sa, &L[buf][0][0][0] + dofs);                                      \
    async16(sa + r64, &L[buf][0][0][0] + dofs + 2048);                         \
    async16(sb, &L[buf][1][0][0] + dofs);                                      \
    async16(sb + r64, &L[buf][1][0][0] + dofs + 2048);                         \
  } while (0)

  // prologue: K-steps 0,1 -> buffers 0,1 (8 loads/thread outstanding)
  STG(0, 0);
  STG(1, 1);

  int niter = K >> 5;   // K-steps of 32
  int cb = 0;
  for (int it = 0; it < niter; ++it) {
    // drain current buffer's 4 loads (issued 2 steps ago); keep newest 4
    if (it + 1 < niter) __builtin_amdgcn_s_waitcnt(WAITCNT_VM4);
    else                __builtin_amdgcn_s_waitcnt(WAITCNT_VM0);
    __builtin_amdgcn_s_barrier();
    if (it + 2 < niter) {
      int pb = cb + 2; if (pb >= 3) pb -= 3;
      STG(pb, it + 2);
    }
    const u16* cA = &L[cb][0][0][0];
    const u16* cB = &L[cb][1][0][0];
    bf16x8 fa[4], fb[4];
#pragma unroll
    for (int mi = 0; mi < 4; mi++)
      fa[mi] = *(const bf16x8*)&cA[(wm + mi * 16 + l15) * 32 + quad * 8];
#pragma unroll
    for (int ni = 0; ni < 4; ni++)
      fb[ni] = *(const bf16x8*)&cB[(wn + ni * 16 + l15) * 32 + quad * 8];
    __builtin_amdgcn_s_setprio(1);
#pragma unroll
    for (int mi = 0; mi < 4; mi++)
#pragma unroll
      for (int ni = 0; ni < 4; ni++)
        acc[mi][ni] = __builtin_amdgcn_mfma_f32_16x16x32_bf16(fa[mi], fb[ni], acc[mi][ni], 0, 0, 0);
    __builtin_amdgcn_s_setprio(0);
    cb = (cb + 1 == 3) ? 0 : cb + 1;
  }
#undef STG
}

// ---------------- fused QKV projection GEMM (bx-partitioned, 128^2 tiles) --
// bx<1024:    Q = xbf*WqT   (M=16384, K=1024, bf16 out, qk-scale folded)
// 1024..1279: K = ctxbf*WkT (M=4096,  K=768,  bf16 out)
// 1280..1535: V = ctxbf*WvT -> Vt[b,h,d,skv] scatter as f16
// XCD swizzle: bx=(bx0&7)*192+bx0>>3 (1536 = 8 x 192, bijective)
__global__ __launch_bounds__(256, 3) void qkv_gemm128(
    const u16* __restrict__ xbf, const u16* __restrict__ ctxbf,
    const u16* __restrict__ WqT, const u16* __restrict__ WkT, const u16* __restrict__ WvT,
    u16* __restrict__ Qb, u16* __restrict__ Kbuf, u16* __restrict__ Vtb, float qscale) {
  int bx0 = blockIdx.x;
  int bx = (bx0 & 7) * 192 + (bx0 >> 3);
  const u16* A; const u16* Bt; u16* C; int K, mode, m0, n0; float scale;
  if (bx < 1024)      { int t = bx;        A = xbf;   Bt = WqT; C = Qb;   K = 1024; mode = 0; scale = qscale; m0 = (t >> 3) * 128; n0 = (t & 7) * 128; }
  else if (bx < 1280) { int t = bx - 1024; A = ctxbf; Bt = WkT; C = Kbuf; K = 768;  mode = 0; scale = 1.0f;   m0 = (t >> 3) * 128; n0 = (t & 7) * 128; }
  else                { int t = bx - 1280; A = ctxbf; Bt = WvT; C = Vtb;  K = 768;  mode = 2; scale = 1.0f;   m0 = (t >> 3) * 128; n0 = (t & 7) * 128; }

  float4v acc[4][4] = {};
  gemm128_core(A, Bt, K, m0, n0, acc);

  int tid = threadIdx.x;
  int w = tid >> 6, lane = tid & 63;
  int l15 = lane & 15, quad = lane >> 4;
  int wm = (w >> 1) * 64, wn = (w & 1) * 64;

  if (mode == 0) {
#pragma unroll
    for (int mi = 0; mi < 4; mi++) {
      int rowb = m0 + wm + mi * 16 + quad * 4;
#pragma unroll
      for (int ni = 0; ni < 4; ni++) {
        int col = n0 + wn + ni * 16 + l15;
#pragma unroll
        for (int r = 0; r < 4; r++)
          C[(size_t)(rowb + r) * 1024 + col] = f2bf(acc[mi][ni][r] * scale);
      }
    }
  } else {
#pragma unroll
    for (int mi = 0; mi < 4; mi++) {
      int rowb = m0 + wm + mi * 16 + quad * 4;
#pragma unroll
      for (int ni = 0; ni < 4; ni++) {
        int col = n0 + wn + ni * 16 + l15;
        int hh = col >> 6, dd = col & 63;
#pragma unroll
        for (int r = 0; r < 4; r++) {
          int rr = rowb + r;
          int b = rr >> 10, skv = rr & 1023;
          _Float16 hv = (_Float16)acc[mi][ni][r];
          C[((((size_t)b * 16 + hh) * 64 + dd) << 10) + skv] = __builtin_bit_cast(u16, hv);
        }
      }
    }
  }
}

// ---------------- output projection: out = attn*WoT^T + bo (fp32, 128^2) ---
// XCD swizzle: bx=(bx0&7)*128+bx0>>3 (1024 = 8 x 128, bijective)
__global__ __launch_bounds__(256, 3) void gemm_bt128(
    const u16* __restrict__ A, const u16* __restrict__ Bt,
    float* __restrict__ C, const float* __restrict__ bias) {
  int bx0 = blockIdx.x;
  int bx = (bx0 & 7) * 128 + (bx0 >> 3);
  int m0 = (bx >> 3) * 128, n0 = (bx & 7) * 128;

  float4v acc[4][4] = {};
  gemm128_core(A, Bt, 1024, m0, n0, acc);

  int tid = threadIdx.x;
  int w = tid >> 6, lane = tid & 63;
  int l15 = lane & 15, quad = lane >> 4;
  int wm = (w >> 1) * 64, wn = (w & 1) * 64;

#pragma unroll
  for (int mi = 0; mi < 4; mi++) {
    int rowb = m0 + wm + mi * 16 + quad * 4;
#pragma unroll
    for (int ni = 0; ni < 4; ni++) {
      int col = n0 + wn + ni * 16 + l15;
      float bv = bias[col];
#pragma unroll
      for (int r = 0; r < 4; r++)
        C[(size_t)(rowb + r) * 1024 + col] = acc[mi][ni][r] + bv;
    }
  }
}

// ---------------- attention v9: per (b,h), O = softmax(Q K^T) V -------------
// grid (SQ/256, B*H), block 512 (8 waves, 32 q each), launch_bounds(512,4).
// KVBLK=128: 8 iterations. LDS 64KB double-buffered, XOR-swizzled.
__global__ __launch_bounds__(512, 4) void attn_kernel(
    const u16* __restrict__ Q, const u16* __restrict__ Kb,
    const u16* __restrict__ Vt, u16* __restrict__ Oout) {
  __shared__ __align__(16) u16 lK[2][8192];   // 128kv x 64d bf16, XOR-swizzled
  __shared__ __align__(16) u16 lV[2][8192];   // 64d x 128kv f16, XOR-swizzled
  int tid = threadIdx.x, w = tid >> 6, lane = tid & 63;
  int l15 = lane & 15, quad = lane >> 4;
  int bh = blockIdx.y, b = bh >> 4, h = bh & 15;
  int q0 = blockIdx.x * 256 + w * 32;

  const u16* Qbase = Q + ((size_t)(b * 4096 + q0)) * 1024 + h * 64;
  const u16* Kbase = Kb + ((size_t)b << 20) + h * 64;
  const u16* Vbase = Vt + ((size_t)bh << 16);

  bf16x8 qf[2][2];
#pragma unroll
  for (int qt = 0; qt < 2; qt++)
#pragma unroll
    for (int c = 0; c < 2; c++)
      qf[qt][c] = *(const bf16x8*)(Qbase + (size_t)(qt * 16 + l15) * 1024 + c * 32 + quad * 8);

  int kr0 = tid >> 3, kx0 = ((tid & 7) ^ (kr0 & 7)) * 8;
  const u16* ks0 = Kbase + (size_t)kr0 * 1024 + kx0;
  const u16* ks1 = ks0 + (size_t)64 * 1024;
  int vd0 = tid >> 4, vc0 = ((tid & 15) ^ (vd0 & 15)) * 8;
  const u16* vs0 = Vbase + (size_t)vd0 * 1024 + vc0;
  const u16* vs1 = vs0 + (size_t)32 * 1024;
  int kdo0 = w * 512, kdo1 = 4096 + w * 512;

  async16(ks0, &lK[0][kdo0]); async16(ks1, &lK[0][kdo1]);
  async16(vs0, &lV[0][kdo0]); async16(vs1, &lV[0][kdo1]);
  ks0 += 131072; ks1 += 131072;
  vs0 += 128; vs1 += 128;

  float4v o[2][4] = {};
  float4v osum[2] = {};
  const half4 ones = {(_Float16)1.0f, (_Float16)1.0f, (_Float16)1.0f, (_Float16)1.0f};

  int lb = l15 & 7;
  int xk0 = ((0 + quad) ^ lb) * 16 + l15 * 128;
  int xk1 = ((4 + quad) ^ lb) * 16 + l15 * 128;
  int qh = quad >> 1, qo = (quad & 1) * 8;
  int vrow = l15 * 256 + qo;

  for (int it = 0; it < 8; ++it) {
    const char* bK = (const char*)lK + (it & 1) * 16384;
    const char* bV = (const char*)lV + (it & 1) * 16384;
    __syncthreads();
    if (it < 7) {
      int nb = (it + 1) & 1;
      async16(ks0, &lK[nb][kdo0]); async16(ks1, &lK[nb][kdo1]);
      async16(vs0, &lV[nb][kdo0]); async16(vs1, &lV[nb][kdo1]);
      ks0 += 131072; ks1 += 131072;
      vs0 += 128; vs1 += 128;
    }
#pragma unroll
    for (int ss = 0; ss < 8; ss++) {
      int sub = (ss + w) & 7;
      int sb = sub * 2048;
      float4v sv[2] = {{0.f, 0.f, 0.f, 0.f}, {0.f, 0.f, 0.f, 0.f}};
      __builtin_amdgcn_s_setprio(1);
#pragma unroll
      for (int c = 0; c < 2; c++) {
        bf16x8 kf = *(const bf16x8*)(bK + sb + (c ? xk1 : xk0));
#pragma unroll
        for (int qt = 0; qt < 2; qt++)
          sv[qt] = __builtin_amdgcn_mfma_f32_16x16x32_bf16(kf, qf[qt][c], sv[qt], 0, 0, 0);
      }
      __builtin_amdgcn_s_setprio(0);
      half4 pf[2];
#pragma unroll
      for (int qt = 0; qt < 2; qt++) {
        float e0 = exp2f(sv[qt][0]), e1 = exp2f(sv[qt][1]);
        float e2 = exp2f(sv[qt][2]), e3 = exp2f(sv[qt][3]);
        half2v p01 = __builtin_bit_cast(half2v, __builtin_amdgcn_cvt_pkrtz(e0, e1));
        half2v p23 = __builtin_bit_cast(half2v, __builtin_amdgcn_cvt_pkrtz(e2, e3));
        pf[qt] = __builtin_shufflevector(p01, p23, 0, 1, 2, 3);
        osum[qt] = __builtin_amdgcn_mfma_f32_16x16x16f16(ones, pf[qt], osum[qt], 0, 0, 0);
      }
      int vbs = vrow + (((sub * 2 + qh) ^ l15) * 16);
      __builtin_amdgcn_s_setprio(1);
#pragma unroll
      for (int dt = 0; dt < 4; dt++) {
        half4 vf = *(const half4*)(bV + dt * 4096 + vbs);
#pragma unroll
        for (int qt = 0; qt < 2; qt++)
          o[qt][dt] = __builtin_amdgcn_mfma_f32_16x16x16f16(vf, pf[qt], o[qt][dt], 0, 0, 0);
      }
      __builtin_amdgcn_s_setprio(0);
    }
  }

#pragma unroll
  for (int qt = 0; qt < 2; qt++) {
    float inv = 1.0f / osum[qt][0];
    u16* Ob = Oout + ((size_t)(b * 4096 + q0 + qt * 16 + l15)) * 1024 + h * 64 + quad * 4;
#pragma unroll
    for (int dt = 0; dt < 4; dt++) {
      ushort4 pk;
      pk.x = f2bf(o[qt][dt][0] * inv);
      pk.y = f2bf(o[qt][dt][1] * inv);
      pk.z = f2bf(o[qt][dt][2] * inv);
      pk.w = f2bf(o[qt][dt][3] * inv);
      *(ushort4*)(Ob + dt * 16) = pk;
    }
  }
}

// ---------------------------------------------------------------------------
extern "C" void kernel_launch(void* const* d_in, const int* in_sizes, int n_in,
                              void* d_out, int out_size, void* d_ws, size_t ws_size,
                              hipStream_t stream) {
  const float* x   = (const float*)d_in[0];
  const float* ctx = (const float*)d_in[1];
  const float* Wq  = (const float*)d_in[2];
  const float* Wk  = (const float*)d_in[3];
  const float* Wv  = (const float*)d_in[4];
  const float* Wo  = (const float*)d_in[5];
  const float* bo  = (const float*)d_in[6];
  float* out = (float*)d_out;

  u16* ws    = (u16*)d_ws;
  u16* xbf   = ws;                  // 16777216 elems (reused as attn_out)
  u16* ctxbf = xbf + 16777216;      // 3145728
  u16* WqT   = ctxbf + 3145728;     // 1048576
  u16* WkT   = WqT + 1048576;       // 786432
  u16* WvT   = WkT + 786432;        // 786432
  u16* WoT   = WvT + 786432;        // 1048576
  u16* Qb    = WoT + 1048576;       // 16777216
  u16* Kbuf  = Qb + 16777216;       // 4194304
  u16* Vtb   = Kbuf + 4194304;      // 4194304 (f16)  -> total ~93 MB
  if (ws_size < (size_t)48758784 * 2) return;  // workspace too small: clean fail

  cvt_kernel<<<19456, 256, 0, stream>>>(x, xbf, ctx, ctxbf);
  twt_kernel<<<dim3(32, 32, 4), dim3(32, 8), 0, stream>>>(Wq, Wk, Wv, Wo, WqT, WkT, WvT, WoT);
  // 1024 Q + 256 K + 256 V blocks of 128^2, 256 threads, m97 structure
  qkv_gemm128<<<dim3(1536), dim3(256), 0, stream>>>(xbf, ctxbf, WqT, WkT, WvT,
                                                    Qb, Kbuf, Vtb, 0.18033688011112042f);
  // attention -> attn_out (bf16, [b, sq, h*64+d]), reusing xbf
  attn_kernel<<<dim3(16, 64), dim3(512), 0, stream>>>(Qb, Kbuf, Vtb, xbf);
  // out = attn_out*Wo + bo (fp32), 128x8 tiles of 128^2
  gemm_bt128<<<dim3(1024), dim3(256), 0, stream>>>(xbf, WoT, out, bo);
}